// Round 2
// baseline (634.253 us; speedup 1.0000x reference)
//
#include <hip/hip_runtime.h>
#include <hip/hip_bf16.h>
#include <math.h>

#define B_    4
#define CIN   128
#define L_    16384
#define NH    4
#define NN    32
#define MT    528
#define CP    2112
#define DIM_  64
#define LT    64
#define MID   8192
#define EPS_  1e-5f
#define KC    66
#define NKC   8

// ---------------- kernel A: x0 (normalized pooled vector at mid position) ----------------
__global__ __launch_bounds__(256) void k_x0(const float* __restrict__ x,
                                            const float* __restrict__ g1,
                                            const float* __restrict__ b1,
                                            float* __restrict__ ws_x0) {
  int b = blockIdx.x;
  __shared__ float xs[CIN];
  __shared__ float tss[CIN];
  __shared__ float pm[CP];
  __shared__ float sqh[NH];
  __shared__ float musd[2];
  int t = threadIdx.x;
  if (t < CIN) xs[t] = x[(size_t)b * CIN * L_ + (size_t)t * L_ + MID];
  if (t < NH) sqh[t] = 0.f;
  __syncthreads();
  if (t == 0) {
    float s = 0.f;
    for (int c = 0; c < CIN; c++) s += xs[c];
    float mu = s / CIN;
    float s2 = 0.f;
    for (int c = 0; c < CIN; c++) { float d = xs[c] - mu; s2 += d * d; }
    musd[0] = mu; musd[1] = rsqrtf(s2 / CIN + EPS_);
  }
  __syncthreads();
  if (t < CIN) {
    // shuffled row r=h*32+i holds original channel c=i*4+h
    int c = ((t & 31) << 2) + (t >> 5);
    tss[t] = (xs[c] - musd[0]) * musd[1] * g1[c] + b1[c];
  }
  __syncthreads();
  for (int idx = t; idx < CP; idx += 256) {
    int h = idx / MT, m = idx - h * MT;
    int i = 0;
    while ((i + 1) * NN - ((i + 1) * i) / 2 <= m) i++;
    int j = i + (m - (i * NN - (i * (i - 1)) / 2));
    float p = tss[h * NN + i] * tss[h * NN + j];
    pm[idx] = p;
    atomicAdd(&sqh[h], p * p);
  }
  __syncthreads();
  for (int idx = t; idx < CP; idx += 256) {
    int h = idx / MT;
    ws_x0[(size_t)b * CP + idx] = pm[idx] * rsqrtf(sqh[h]);
  }
}

// ---------------- kernel B: attention logits per position ----------------
__global__ __launch_bounds__(256) void k_logits(const float* __restrict__ x,
                                                const float* __restrict__ g1,
                                                const float* __restrict__ b1,
                                                const float* __restrict__ ws_x0,
                                                float* __restrict__ ws_a) {
  int blk = blockIdx.x;
  int b = blk >> 8;
  int l0 = (blk & 255) << 6;
  __shared__ float ts[CIN][LT + 1];
  __shared__ unsigned char iu_s[MT], ju_s[MT];
  __shared__ float mu_s[LT], isd_s[LT];
  __shared__ float part[4][LT], part2[4][LT];
  int t = threadIdx.x;
  int l = t & 63, q = t >> 6;
  for (int m = t; m < MT; m += 256) {
    int i = 0;
    while ((i + 1) * NN - ((i + 1) * i) / 2 <= m) i++;
    iu_s[m] = (unsigned char)i;
    ju_s[m] = (unsigned char)(i + (m - (i * NN - (i * (i - 1)) / 2)));
  }
  const float* xb = x + (size_t)b * CIN * L_ + l0;
  float s = 0.f, s2 = 0.f;
  for (int r = q; r < CIN; r += 4) {
    int c = ((r & 31) << 2) + (r >> 5);
    float v = xb[(size_t)c * L_ + l];
    s += v; s2 += v * v;
    ts[r][l] = v;
  }
  part[q][l] = s; part2[q][l] = s2;
  __syncthreads();
  if (t < LT) {
    float su = part[0][t] + part[1][t] + part[2][t] + part[3][t];
    float su2 = part2[0][t] + part2[1][t] + part2[2][t] + part2[3][t];
    float mu = su * (1.f / CIN);
    float var = su2 * (1.f / CIN) - mu * mu;
    mu_s[t] = mu; isd_s[t] = rsqrtf(var + EPS_);
  }
  __syncthreads();
  for (int r = q; r < CIN; r += 4) {
    int c = ((r & 31) << 2) + (r >> 5);
    ts[r][l] = (ts[r][l] - mu_s[l]) * isd_s[l] * g1[c] + b1[c];
  }
  __syncthreads();
  for (int h = 0; h < NH; h++) {
    const float* x0h = ws_x0 + (size_t)b * CP + h * MT;
    float dp = 0.f, sq = 0.f;
    for (int m = q * 132; m < q * 132 + 132; m++) {
      float p = ts[h * NN + iu_s[m]][l] * ts[h * NN + ju_s[m]][l];
      dp += x0h[m] * p;
      sq += p * p;
    }
    part[q][l] = dp; part2[q][l] = sq;
    __syncthreads();
    if (t < LT) {
      float d = part[0][t] + part[1][t] + part[2][t] + part[3][t];
      float ss = part2[0][t] + part2[1][t] + part2[2][t] + part2[3][t];
      ws_a[((size_t)b * NH + h) * L_ + l0 + t] = d * rsqrtf(ss);
    }
    __syncthreads();
  }
}

// ---------------- kernel C: softmax stats over L ----------------
__global__ __launch_bounds__(256) void k_softmax(const float* __restrict__ ws_a,
                                                 float* __restrict__ ws_stats) {
  int bh = blockIdx.x;
  const float* a = ws_a + (size_t)bh * L_;
  __shared__ float red[256];
  int t = threadIdx.x;
  float mx = -1e30f;
  for (int i = t; i < L_; i += 256) mx = fmaxf(mx, a[i]);
  red[t] = mx; __syncthreads();
  for (int s = 128; s > 0; s >>= 1) {
    if (t < s) red[t] = fmaxf(red[t], red[t + s]);
    __syncthreads();
  }
  float amax = red[0];
  __syncthreads();
  float sm = 0.f;
  for (int i = t; i < L_; i += 256) sm += expf(a[i] - amax);
  red[t] = sm; __syncthreads();
  for (int s = 128; s > 0; s >>= 1) {
    if (t < s) red[t] += red[t + s];
    __syncthreads();
  }
  if (t == 0) { ws_stats[bh * 2] = amax; ws_stats[bh * 2 + 1] = red[0]; }
}

// ---------------- kernel D: fused attn-weighted GEMM + norm2 + fc1 + gelu ----------------
struct __align__(16) SmemD {
  __hip_bfloat16 ts[CIN][LT];           // 16384 B
  unsigned char iu_s[MT], ju_s[MT];     // 1056
  float attnL[NH][LT];                  // 1024
  float mu_s[LT], isd_s[LT];            // 512
  float part[4][LT], part2[4][LT];      // 2048
  union __align__(16) {
    struct { float pw[KC][LT]; float wb[DIM_][KC + 1]; } g;   // 34048
    struct { float zt[LT][DIM_ + 1]; float fw[DIM_][DIM_ + 1]; } tl; // 33280
  } u;
};

__global__ __launch_bounds__(256) void k_main(const float* __restrict__ x,
      const float* __restrict__ g1, const float* __restrict__ b1,
      const float* __restrict__ dr_w, const float* __restrict__ dr_b,
      const float* __restrict__ g2, const float* __restrict__ b2,
      const float* __restrict__ fc1_w, const float* __restrict__ fc1_b,
      const float* __restrict__ ws_a, const float* __restrict__ ws_stats,
      float* __restrict__ out) {
  __shared__ SmemD sm;
  int blk = blockIdx.x;
  int b = blk >> 8;
  int l0 = (blk & 255) << 6;
  int t = threadIdx.x;
  int l = t & 63, q = t >> 6;

  for (int m = t; m < MT; m += 256) {
    int i = 0;
    while ((i + 1) * NN - ((i + 1) * i) / 2 <= m) i++;
    sm.iu_s[m] = (unsigned char)i;
    sm.ju_s[m] = (unsigned char)(i + (m - (i * NN - (i * (i - 1)) / 2)));
  }
  {
    float amax = ws_stats[(b * NH + q) * 2];
    float asum = ws_stats[(b * NH + q) * 2 + 1];
    float av = ws_a[((size_t)b * NH + q) * L_ + l0 + l];
    sm.attnL[q][l] = expf(av - amax) * ((float)L_ / asum);
  }
  const float* xb = x + (size_t)b * CIN * L_ + l0;
  float s = 0.f, s2 = 0.f;
  for (int r = q; r < CIN; r += 4) {
    int c = ((r & 31) << 2) + (r >> 5);
    float v = xb[(size_t)c * L_ + l];
    s += v; s2 += v * v;
    sm.ts[r][l] = __float2bfloat16(v);
  }
  sm.part[q][l] = s; sm.part2[q][l] = s2;
  __syncthreads();
  if (t < LT) {
    float su = sm.part[0][t] + sm.part[1][t] + sm.part[2][t] + sm.part[3][t];
    float su2 = sm.part2[0][t] + sm.part2[1][t] + sm.part2[2][t] + sm.part2[3][t];
    float mu = su * (1.f / CIN);
    float var = su2 * (1.f / CIN) - mu * mu;
    sm.mu_s[t] = mu; sm.isd_s[t] = rsqrtf(var + EPS_);
  }
  __syncthreads();
  for (int r = q; r < CIN; r += 4) {
    int c = ((r & 31) << 2) + (r >> 5);
    float v = __bfloat162float(sm.ts[r][l]);
    sm.ts[r][l] = __float2bfloat16((v - sm.mu_s[l]) * sm.isd_s[l] * g1[c] + b1[c]);
  }

  int og = t >> 4, lg = t & 15;
  int o0 = og << 2;
  float acc[4][4] = {{0.f}};
  for (int h = 0; h < NH; h++) {
    for (int kc = 0; kc < NKC; kc++) {
      __syncthreads();
      for (int idx = t; idx < KC * LT; idx += 256) {
        int kk = idx >> 6, ll = idx & 63;
        int m = kc * KC + kk;
        float p = __bfloat162float(sm.ts[h * NN + sm.iu_s[m]][ll]) *
                  __bfloat162float(sm.ts[h * NN + sm.ju_s[m]][ll]);
        sm.u.g.pw[kk][ll] = p * sm.attnL[h][ll];
      }
      const float* wsrc = dr_w + h * MT + kc * KC;
      for (int idx = t; idx < DIM_ * KC; idx += 256) {
        int o = idx / KC;
        int kk = idx - o * KC;
        sm.u.g.wb[o][kk] = wsrc[(size_t)o * CP + kk];
      }
      __syncthreads();
#pragma unroll 2
      for (int kk = 0; kk < KC; kk++) {
        float4 pv = *(const float4*)&sm.u.g.pw[kk][lg << 2];
        float w0 = sm.u.g.wb[o0][kk];
        float w1 = sm.u.g.wb[o0 + 1][kk];
        float w2 = sm.u.g.wb[o0 + 2][kk];
        float w3 = sm.u.g.wb[o0 + 3][kk];
        acc[0][0] = fmaf(w0, pv.x, acc[0][0]); acc[0][1] = fmaf(w0, pv.y, acc[0][1]);
        acc[0][2] = fmaf(w0, pv.z, acc[0][2]); acc[0][3] = fmaf(w0, pv.w, acc[0][3]);
        acc[1][0] = fmaf(w1, pv.x, acc[1][0]); acc[1][1] = fmaf(w1, pv.y, acc[1][1]);
        acc[1][2] = fmaf(w1, pv.z, acc[1][2]); acc[1][3] = fmaf(w1, pv.w, acc[1][3]);
        acc[2][0] = fmaf(w2, pv.x, acc[2][0]); acc[2][1] = fmaf(w2, pv.y, acc[2][1]);
        acc[2][2] = fmaf(w2, pv.z, acc[2][2]); acc[2][3] = fmaf(w2, pv.w, acc[2][3]);
        acc[3][0] = fmaf(w3, pv.x, acc[3][0]); acc[3][1] = fmaf(w3, pv.y, acc[3][1]);
        acc[3][2] = fmaf(w3, pv.z, acc[3][2]); acc[3][3] = fmaf(w3, pv.w, acc[3][3]);
      }
    }
  }
  __syncthreads();
  for (int oo = 0; oo < 4; oo++)
    for (int ll = 0; ll < 4; ll++)
      sm.u.tl.zt[(lg << 2) + ll][o0 + oo] = acc[oo][ll] + dr_b[o0 + oo];
  for (int idx = t; idx < DIM_ * DIM_; idx += 256) {
    int o = idx >> 6, c = idx & 63;
    sm.u.tl.fw[o][c] = fc1_w[idx];
  }
  __syncthreads();
  if (t < LT) {
    float su = 0.f, su2 = 0.f;
    for (int c = 0; c < DIM_; c++) { float v = sm.u.tl.zt[t][c]; su += v; su2 += v * v; }
    float mu = su * (1.f / DIM_);
    float var = su2 * (1.f / DIM_) - mu * mu;
    float isd = rsqrtf(var + EPS_);
    for (int c = 0; c < DIM_; c++)
      sm.u.tl.zt[t][c] = (sm.u.tl.zt[t][c] - mu) * isd * g2[c] + b2[c];
  }
  __syncthreads();
  float* ob = out + (size_t)b * DIM_ * L_ + l0 + l;
  for (int k = 0; k < 16; k++) {
    int o2 = q * 16 + k;
    float sv = fc1_b[o2];
    for (int c = 0; c < DIM_; c++) sv = fmaf(sm.u.tl.fw[o2][c], sm.u.tl.zt[l][c], sv);
    float r = 0.5f * sv * (1.f + erff(sv * 0.70710678118f));
    ob[(size_t)o2 * L_] = r;
  }
}

extern "C" void kernel_launch(void* const* d_in, const int* in_sizes, int n_in,
                              void* d_out, int out_size, void* d_ws, size_t ws_size,
                              hipStream_t stream) {
  const float* x    = (const float*)d_in[0];
  const float* n1w  = (const float*)d_in[1];
  const float* n1b  = (const float*)d_in[2];
  const float* drw  = (const float*)d_in[3];
  const float* drb  = (const float*)d_in[4];
  const float* n2w  = (const float*)d_in[5];
  const float* n2b  = (const float*)d_in[6];
  const float* fc1w = (const float*)d_in[7];
  const float* fc1b = (const float*)d_in[8];
  float* out = (float*)d_out;
  float* ws = (float*)d_ws;
  float* ws_x0 = ws;                       // 4*2112 floats
  float* ws_a  = ws_x0 + B_ * CP;          // 4*4*16384 floats
  float* ws_st = ws_a + (size_t)B_ * NH * L_;  // 32 floats

  hipLaunchKernelGGL(k_x0, dim3(B_), dim3(256), 0, stream, x, n1w, n1b, ws_x0);
  hipLaunchKernelGGL(k_logits, dim3(B_ * (L_ / LT)), dim3(256), 0, stream,
                     x, n1w, n1b, ws_x0, ws_a);
  hipLaunchKernelGGL(k_softmax, dim3(B_ * NH), dim3(256), 0, stream, ws_a, ws_st);
  hipLaunchKernelGGL(k_main, dim3(B_ * (L_ / LT)), dim3(256), 0, stream,
                     x, n1w, n1b, drw, drb, n2w, n2b, fc1w, fc1b, ws_a, ws_st, out);
}

// Round 3
// 209.546 us; speedup vs baseline: 3.0268x; 3.0268x over previous
//
#include <hip/hip_runtime.h>
#include <hip/hip_bf16.h>
#include <math.h>

#define B_    4
#define CIN   128
#define L_    16384
#define NH    4
#define NN    32
#define MT    528
#define CP    2112
#define DIM_  64
#define LT    64
#define MID   8192
#define EPS_  1e-5f

// padded-K layout: each tri row i padded to 8-aligned j-blocks.
// per head: 80 k-blocks of 8 -> 640; total K' = 2560.
#define KPH   640
#define KTOT  2560
#define NKS   80          // ksteps of 32 total (KTOT/32)
#define WSWN  (KTOT * DIM_)   // 163840 bf16 slots
#define FSWN  (2 * 4 * 64 * 8) // 4096 bf16 slots

typedef __attribute__((ext_vector_type(8))) short short8;
typedef __attribute__((ext_vector_type(4))) float float4v;

__device__ inline unsigned short f2bf(float f) {
  unsigned u = __float_as_uint(f);
  unsigned r = (u + 0x7fffu + ((u >> 16) & 1u)) >> 16;
  return (unsigned short)r;
}
__device__ inline float bf2f(unsigned short h) {
  return __uint_as_float(((unsigned)h) << 16);
}

// decode head-local k-block (0..79) -> (i, jb)
__device__ inline void kb_decode(int kbh, int& i, int& jb) {
  if (kbh < 32)      { i = kbh >> 2;              jb = kbh & 3; }
  else if (kbh < 56) { int r = kbh - 32; int d = r / 3; i = 8 + d;  jb = 1 + (r - 3 * d); }
  else if (kbh < 72) { int r = kbh - 56; i = 16 + (r >> 1); jb = 2 + (r & 1); }
  else               { i = 24 + (kbh - 72);        jb = 3; }
}

// ---------------- prep: bf16-swizzled weights for MFMA A-fragments ----------------
__global__ __launch_bounds__(256) void k_prep(const float* __restrict__ dr_w,
                                              const float* __restrict__ fc1_w,
                                              unsigned short* __restrict__ wsw,
                                              unsigned short* __restrict__ fsw) {
  int s = blockIdx.x * 256 + threadIdx.x;
  if (s < WSWN) {
    int j    = s & 7;
    int lane = (s >> 3) & 63;
    int ot   = (s >> 9) & 3;
    int ksg  = s >> 11;
    int o  = ot * 16 + (lane & 15);
    int kp = ksg * 32 + (lane >> 4) * 8 + j;   // padded-K index 0..2559
    int h  = kp / KPH;
    int kk = kp - h * KPH;
    int kb = kk >> 3, jo = kk & 7;
    int i, jb; kb_decode(kb, i, jb);
    int jch = jb * 8 + jo;
    float val = 0.f;
    if (jch >= i) {
      int fi = 32 * i - (i * (i - 1)) / 2;
      int m  = h * MT + fi + (jch - i);
      val = dr_w[(size_t)o * CP + m];
    }
    wsw[s] = f2bf(val);
  } else if (s < WSWN + FSWN) {
    int s2 = s - WSWN;
    int j    = s2 & 7;
    int lane = (s2 >> 3) & 63;
    int ot   = (s2 >> 9) & 3;
    int ks2  = s2 >> 11;
    int o = ot * 16 + (lane & 15);
    int c = ks2 * 32 + (lane >> 4) * 8 + j;
    fsw[s2] = f2bf(fc1_w[o * DIM_ + c]);
  }
}

// ---------------- kernel A: x0 (normalized pooled vector at mid position) ----------------
__global__ __launch_bounds__(256) void k_x0(const float* __restrict__ x,
                                            const float* __restrict__ g1,
                                            const float* __restrict__ b1,
                                            float* __restrict__ ws_x0) {
  int b = blockIdx.x;
  __shared__ float xs[CIN];
  __shared__ float tss[CIN];
  __shared__ float pm[CP];
  __shared__ float sqh[NH];
  __shared__ float musd[2];
  int t = threadIdx.x;
  if (t < CIN) xs[t] = x[(size_t)b * CIN * L_ + (size_t)t * L_ + MID];
  if (t < NH) sqh[t] = 0.f;
  __syncthreads();
  if (t == 0) {
    float s = 0.f;
    for (int c = 0; c < CIN; c++) s += xs[c];
    float mu = s / CIN;
    float s2 = 0.f;
    for (int c = 0; c < CIN; c++) { float d = xs[c] - mu; s2 += d * d; }
    musd[0] = mu; musd[1] = rsqrtf(s2 / CIN + EPS_);
  }
  __syncthreads();
  if (t < CIN) {
    int c = ((t & 31) << 2) + (t >> 5);
    tss[t] = (xs[c] - musd[0]) * musd[1] * g1[c] + b1[c];
  }
  __syncthreads();
  for (int idx = t; idx < CP; idx += 256) {
    int h = idx / MT, m = idx - h * MT;
    int i = 0;
    while ((i + 1) * NN - ((i + 1) * i) / 2 <= m) i++;
    int j = i + (m - (i * NN - (i * (i - 1)) / 2));
    float p = tss[h * NN + i] * tss[h * NN + j];
    pm[idx] = p;
    atomicAdd(&sqh[h], p * p);
  }
  __syncthreads();
  for (int idx = t; idx < CP; idx += 256) {
    int h = idx / MT;
    ws_x0[(size_t)b * CP + idx] = pm[idx] * rsqrtf(sqh[h]);
  }
}

// ---------------- kernel B: attention logits (register-resident t, closed-form ||p||) ----------------
__global__ __launch_bounds__(256, 4) void k_logits(const float* __restrict__ x,
                                                   const float* __restrict__ g1,
                                                   const float* __restrict__ b1,
                                                   const float* __restrict__ ws_x0,
                                                   float* __restrict__ ws_a) {
  int blk = blockIdx.x;
  int b = blk >> 8;
  int l0 = (blk & 255) << 6;
  int t = threadIdx.x;
  int l = t & 63, q = t >> 6;
  __shared__ float part[4][64], part2[4][64], mu_s[64], isd_s[64];

  float tv[32];
  const float* xb = x + (size_t)b * CIN * L_ + l0;
  float s = 0.f, s2 = 0.f;
#pragma unroll
  for (int cc = 0; cc < 32; cc++) {
    int co = cc * 4 + q;                       // shuffled row h=q, i=cc  ->  orig channel
    float v = xb[(size_t)co * L_ + l];
    tv[cc] = v; s += v; s2 += v * v;
  }
  part[q][l] = s; part2[q][l] = s2;
  __syncthreads();
  if (t < 64) {
    float su = part[0][t] + part[1][t] + part[2][t] + part[3][t];
    float su2 = part2[0][t] + part2[1][t] + part2[2][t] + part2[3][t];
    float mu = su * (1.f / CIN);
    float var = su2 * (1.f / CIN) - mu * mu;
    mu_s[t] = mu; isd_s[t] = rsqrtf(var + EPS_);
  }
  __syncthreads();
  float mu = mu_s[l], isd = isd_s[l];
#pragma unroll
  for (int cc = 0; cc < 32; cc++) {
    int co = cc * 4 + q;
    tv[cc] = (tv[cc] - mu) * isd * g1[co] + b1[co];
  }
  // ||p||^2 = 0.5*(S^2 + sum t^4), S = sum t^2
  float S = 0.f, T4 = 0.f;
#pragma unroll
  for (int i = 0; i < 32; i++) { float t2 = tv[i] * tv[i]; S += t2; T4 = fmaf(t2, t2, T4); }
  // dp = sum_{i<=j} x0[m] t_i t_j  (x0 reads are wave-uniform -> scalar loads)
  const float* x0h = ws_x0 + (size_t)b * CP + q * MT;
  float dp = 0.f;
  int m = 0;
#pragma unroll
  for (int i = 0; i < 32; i++) {
    float vi = 0.f;
#pragma unroll
    for (int j = i; j < 32; j++) { vi = fmaf(x0h[m], tv[j], vi); m++; }
    dp = fmaf(tv[i], vi, dp);
  }
  float logit = dp * rsqrtf(0.5f * (S * S + T4));
  ws_a[((size_t)b * NH + q) * L_ + l0 + l] = logit;
}

// ---------------- kernel C: softmax stats over L ----------------
__global__ __launch_bounds__(256) void k_softmax(const float* __restrict__ ws_a,
                                                 float* __restrict__ ws_stats) {
  int bh = blockIdx.x;
  const float* a = ws_a + (size_t)bh * L_;
  __shared__ float red[256];
  int t = threadIdx.x;
  float mx = -1e30f;
  for (int i = t; i < L_; i += 256) mx = fmaxf(mx, a[i]);
  red[t] = mx; __syncthreads();
  for (int s = 128; s > 0; s >>= 1) {
    if (t < s) red[t] = fmaxf(red[t], red[t + s]);
    __syncthreads();
  }
  float amax = red[0];
  __syncthreads();
  float sm = 0.f;
  for (int i = t; i < L_; i += 256) sm += expf(a[i] - amax);
  red[t] = sm; __syncthreads();
  for (int s = 128; s > 0; s >>= 1) {
    if (t < s) red[t] += red[t + s];
    __syncthreads();
  }
  if (t == 0) { ws_stats[bh * 2] = amax; ws_stats[bh * 2 + 1] = red[0]; }
}

// ---------------- kernel D: MFMA main ----------------
// LDS: p2 frag buffer [ltile4][ks5][quad4][n16][8] bf16 (20480B) U zb[64][65] f32 (16640B)
//      ut[64][128] bf16 xor-swizzled (16384B)        U zn2 [ltile4][ks2:2][quad4][n16][8] (8192B)
struct __align__(16) SmemM {
  union __align__(16) { unsigned short p2[4 * 5 * 4 * 16 * 8]; float zb[64 * 65]; } u1;
  union __align__(16) { unsigned short ut[64 * 128]; unsigned short zn2[4 * 2 * 4 * 16 * 8]; } u2;
  float part[4][64], part2[4][64], mu_s[64], isd_s[64];
};

__device__ inline int utidx(int l, int c) {
  return l * 128 + ((((c >> 3) ^ (l & 7))) << 3) + (c & 7);
}

__global__ __launch_bounds__(256, 3) void k_main(const float* __restrict__ x,
      const float* __restrict__ g1, const float* __restrict__ b1,
      const float* __restrict__ dr_b,
      const float* __restrict__ g2, const float* __restrict__ b2,
      const float* __restrict__ fc1_b,
      const unsigned short* __restrict__ wsw, const unsigned short* __restrict__ fsw,
      const float* __restrict__ ws_a, const float* __restrict__ ws_stats,
      float* __restrict__ out) {
  __shared__ SmemM sm;
  int blk = blockIdx.x;
  int b = blk >> 8;
  int l0 = (blk & 255) << 6;
  int t = threadIdx.x;
  int l = t & 63, q = t >> 6;   // q = wave id = l-tile; l = lane

  // attn weight for head q at position l (folded as sqrt into u)
  float amax = ws_stats[(b * NH + q) * 2];
  float asum = ws_stats[(b * NH + q) * 2 + 1];
  float av = ws_a[((size_t)b * NH + q) * L_ + l0 + l];
  float sa = sqrtf(expf(av - amax) * ((float)L_ / asum));

  // ---- stage x (head q's 32 shuffled channels) into ut, LN stats in flight ----
  const float* xb = x + (size_t)b * CIN * L_ + l0;
  float s = 0.f, s2 = 0.f;
#pragma unroll
  for (int cb = 0; cb < 4; cb++) {
    unsigned short pk[8];
#pragma unroll
    for (int e = 0; e < 8; e++) {
      int cc = cb * 8 + e;
      int co = cc * 4 + q;
      float v = xb[(size_t)co * L_ + l];
      s += v; s2 += v * v;
      pk[e] = f2bf(v);
    }
    *(short8*)&sm.u2.ut[l * 128 + (((q * 4 + cb) ^ (l & 7)) << 3)] = *(short8*)pk;
  }
  sm.part[q][l] = s; sm.part2[q][l] = s2;
  __syncthreads();
  if (t < 64) {
    float su = sm.part[0][t] + sm.part[1][t] + sm.part[2][t] + sm.part[3][t];
    float su2 = sm.part2[0][t] + sm.part2[1][t] + sm.part2[2][t] + sm.part2[3][t];
    float mu = su * (1.f / CIN);
    float var = su2 * (1.f / CIN) - mu * mu;
    sm.mu_s[t] = mu; sm.isd_s[t] = rsqrtf(var + EPS_);
  }
  __syncthreads();
  // ---- normalize + fold sqrt(attn): u = ((x-mu)*isd*g+b) * sa ----
  {
    float mu = sm.mu_s[l], isd = sm.isd_s[l];
#pragma unroll
    for (int cb = 0; cb < 4; cb++) {
      unsigned short* pp = &sm.u2.ut[l * 128 + (((q * 4 + cb) ^ (l & 7)) << 3)];
      short8 v8 = *(short8*)pp;
      unsigned short pk[8];
#pragma unroll
      for (int e = 0; e < 8; e++) {
        int cc = cb * 8 + e;
        int co = cc * 4 + q;
        float tvv = (bf2f((unsigned short)v8[e]) - mu) * isd * g1[co] + b1[co];
        pk[e] = f2bf(tvv * sa);
      }
      *(short8*)pp = *(short8*)pk;
    }
  }
  __syncthreads();

  // ---- main GEMM: 16 chunks (4/head), KCHUNK=160 (20 k-blocks, 5 ksteps) ----
  float4v acc[4];
  acc[0] = (float4v)0.f; acc[1] = (float4v)0.f; acc[2] = (float4v)0.f; acc[3] = (float4v)0.f;
  int tl = l;
  int ltile = l >> 4, n = l & 15;

  for (int cc16 = 0; cc16 < 16; cc16++) {
    int h = cc16 >> 2;
    int cpart = cc16 & 3;
    // build P chunk: thread handles k-blocks q*5 .. q*5+4
#pragma unroll
    for (int s5 = 0; s5 < 5; s5++) {
      int kbl = q * 5 + s5;            // 0..19
      int kbh = cpart * 20 + kbl;      // 0..79
      int i, jb; kb_decode(kbh, i, jb);
      float ui = bf2f(sm.u2.ut[utidx(l, h * 32 + i)]);
      short8 ub = *(short8*)&sm.u2.ut[l * 128 + (((h * 4 + jb) ^ (l & 7)) << 3)];
      unsigned short pk[8];
#pragma unroll
      for (int e = 0; e < 8; e++) pk[e] = f2bf(ui * bf2f((unsigned short)ub[e]));
      int ks = kbl >> 2, quad = kbl & 3;
      *(short8*)&sm.u1.p2[(((ltile * 5 + ks) * 4 + quad) * 16 + n) * 8] = *(short8*)pk;
    }
    __syncthreads();
    // consume: 5 ksteps, wave q owns l-tile q, loops o-tiles
    const unsigned short* wbase = wsw + (size_t)(cc16 * 5) * 2048 + tl * 8;
#pragma unroll
    for (int ks = 0; ks < 5; ks++) {
      short8 bf = *(short8*)&sm.u1.p2[((q * 5 + ks) * 64 + tl) * 8];
      const unsigned short* wk = wbase + ks * 2048;
      short8 a0 = *(const short8*)(wk);
      short8 a1 = *(const short8*)(wk + 512);
      short8 a2 = *(const short8*)(wk + 1024);
      short8 a3 = *(const short8*)(wk + 1536);
      acc[0] = __builtin_amdgcn_mfma_f32_16x16x32_bf16(a0, bf, acc[0], 0, 0, 0);
      acc[1] = __builtin_amdgcn_mfma_f32_16x16x32_bf16(a1, bf, acc[1], 0, 0, 0);
      acc[2] = __builtin_amdgcn_mfma_f32_16x16x32_bf16(a2, bf, acc[2], 0, 0, 0);
      acc[3] = __builtin_amdgcn_mfma_f32_16x16x32_bf16(a3, bf, acc[3], 0, 0, 0);
    }
    __syncthreads();
  }

  // ---- epilogue: z -> zb (fp32), norm2, zn2 (bf16 frags), fc1 MFMA, GELU ----
  int quad = tl >> 4;
#pragma unroll
  for (int ot = 0; ot < 4; ot++) {
#pragma unroll
    for (int r = 0; r < 4; r++) {
      int o = ot * 16 + quad * 4 + r;
      sm.u1.zb[(q * 16 + n) * 65 + o] = acc[ot][r] + dr_b[o];
    }
  }
  __syncthreads();
  {
    float ss = 0.f, ss2 = 0.f;
#pragma unroll
    for (int k = 0; k < 16; k++) {
      float v = sm.u1.zb[l * 65 + q * 16 + k];
      ss += v; ss2 += v * v;
    }
    sm.part[q][l] = ss; sm.part2[q][l] = ss2;
  }
  __syncthreads();
  if (t < 64) {
    float su = sm.part[0][t] + sm.part[1][t] + sm.part[2][t] + sm.part[3][t];
    float su2 = sm.part2[0][t] + sm.part2[1][t] + sm.part2[2][t] + sm.part2[3][t];
    float mu = su * (1.f / DIM_);
    float var = su2 * (1.f / DIM_) - mu * mu;
    sm.mu_s[t] = mu; sm.isd_s[t] = rsqrtf(var + EPS_);
  }
  __syncthreads();
  {
    float mu2 = sm.mu_s[l], isd2 = sm.isd_s[l];
#pragma unroll
    for (int kk = 0; kk < 2; kk++) {
      int kb2 = q * 2 + kk;
      int c0 = kb2 * 8;
      unsigned short pk[8];
#pragma unroll
      for (int e = 0; e < 8; e++) {
        int c = c0 + e;
        float v = (sm.u1.zb[l * 65 + c] - mu2) * isd2 * g2[c] + b2[c];
        pk[e] = f2bf(v);
      }
      int ks2 = kb2 >> 2, qd2 = kb2 & 3;
      *(short8*)&sm.u2.zn2[(((ltile * 2 + ks2) * 4 + qd2) * 16 + n) * 8] = *(short8*)pk;
    }
  }
  __syncthreads();
  float4v acc2[4];
  acc2[0] = (float4v)0.f; acc2[1] = (float4v)0.f; acc2[2] = (float4v)0.f; acc2[3] = (float4v)0.f;
#pragma unroll
  for (int ks2 = 0; ks2 < 2; ks2++) {
    short8 bz = *(short8*)&sm.u2.zn2[((q * 2 + ks2) * 64 + tl) * 8];
    const unsigned short* fk = fsw + ks2 * 2048 + tl * 8;
    short8 f0 = *(const short8*)(fk);
    short8 f1 = *(const short8*)(fk + 512);
    short8 f2 = *(const short8*)(fk + 1024);
    short8 f3 = *(const short8*)(fk + 1536);
    acc2[0] = __builtin_amdgcn_mfma_f32_16x16x32_bf16(f0, bz, acc2[0], 0, 0, 0);
    acc2[1] = __builtin_amdgcn_mfma_f32_16x16x32_bf16(f1, bz, acc2[1], 0, 0, 0);
    acc2[2] = __builtin_amdgcn_mfma_f32_16x16x32_bf16(f2, bz, acc2[2], 0, 0, 0);
    acc2[3] = __builtin_amdgcn_mfma_f32_16x16x32_bf16(f3, bz, acc2[3], 0, 0, 0);
  }
#pragma unroll
  for (int ot = 0; ot < 4; ot++) {
#pragma unroll
    for (int r = 0; r < 4; r++) {
      int o2 = ot * 16 + quad * 4 + r;
      float sv = acc2[ot][r] + fc1_b[o2];
      float g = 0.5f * sv * (1.f + erff(sv * 0.70710678118f));
      out[((size_t)b * DIM_ + o2) * L_ + l0 + q * 16 + n] = g;
    }
  }
}

extern "C" void kernel_launch(void* const* d_in, const int* in_sizes, int n_in,
                              void* d_out, int out_size, void* d_ws, size_t ws_size,
                              hipStream_t stream) {
  const float* x    = (const float*)d_in[0];
  const float* n1w  = (const float*)d_in[1];
  const float* n1b  = (const float*)d_in[2];
  const float* drw  = (const float*)d_in[3];
  const float* drb  = (const float*)d_in[4];
  const float* n2w  = (const float*)d_in[5];
  const float* n2b  = (const float*)d_in[6];
  const float* fc1w = (const float*)d_in[7];
  const float* fc1b = (const float*)d_in[8];
  float* out = (float*)d_out;
  float* ws = (float*)d_ws;
  float* ws_x0 = ws;                                   // 4*2112
  float* ws_a  = ws_x0 + B_ * CP;                      // 4*4*16384
  float* ws_st = ws_a + (size_t)B_ * NH * L_;          // 32
  unsigned short* wsw = (unsigned short*)(ws_st + 32); // 163840 bf16
  unsigned short* fsw = wsw + WSWN;                    // 4096 bf16

  hipLaunchKernelGGL(k_prep, dim3((WSWN + FSWN) / 256), dim3(256), 0, stream, drw, fc1w, wsw, fsw);
  hipLaunchKernelGGL(k_x0, dim3(B_), dim3(256), 0, stream, x, n1w, n1b, ws_x0);
  hipLaunchKernelGGL(k_logits, dim3(B_ * (L_ / LT)), dim3(256), 0, stream,
                     x, n1w, n1b, ws_x0, ws_a);
  hipLaunchKernelGGL(k_softmax, dim3(B_ * NH), dim3(256), 0, stream, ws_a, ws_st);
  hipLaunchKernelGGL(k_main, dim3(B_ * (L_ / LT)), dim3(256), 0, stream,
                     x, n1w, n1b, drb, n2w, n2b, fc1b, wsw, fsw, ws_a, ws_st, out);
}

// Round 5
// 204.624 us; speedup vs baseline: 3.0996x; 1.0241x over previous
//
#include <hip/hip_runtime.h>
#include <hip/hip_bf16.h>
#include <math.h>

#define B_    4
#define CIN   128
#define L_    16384
#define NH    4
#define NN    32
#define MT    528
#define CP    2112
#define DIM_  64
#define LT    64
#define MID   8192
#define EPS_  1e-5f

// padded-K layout (R3-proven): per head 80 k-blocks of 8; heads contiguous in K.
#define KPH   640
#define KTOT  2560
#define WSWN  (KTOT * DIM_)       // 163840 bf16 slots
#define FSWN  (2 * 4 * 64 * 8)    // 4096 bf16 slots

typedef __attribute__((ext_vector_type(8))) short short8;
typedef __attribute__((ext_vector_type(4))) float float4v;

__device__ inline unsigned short f2bf(float f) {
  unsigned u = __float_as_uint(f);
  unsigned r = (u + 0x7fffu + ((u >> 16) & 1u)) >> 16;
  return (unsigned short)r;
}
__device__ inline float bf2f(unsigned short h) {
  return __uint_as_float(((unsigned)h) << 16);
}

// decode head-local k-block (0..79) -> (i, jb)
__device__ inline void kb_decode(int id, int& i, int& jb) {
  if (id < 32)      { i = id >> 2;               jb = id & 3; }
  else if (id < 56) { int r = id - 32; int d = r / 3; i = 8 + d;  jb = 1 + (r - 3 * d); }
  else if (id < 72) { int r = id - 56; i = 16 + (r >> 1); jb = 2 + (r & 1); }
  else              { i = 24 + (id - 72);         jb = 3; }
}

// ---------------- prep: bf16-swizzled weights for MFMA A-fragments (R3 verbatim) ----------------
__global__ __launch_bounds__(256) void k_prep(const float* __restrict__ dr_w,
                                              const float* __restrict__ fc1_w,
                                              unsigned short* __restrict__ wsw,
                                              unsigned short* __restrict__ fsw) {
  int s = blockIdx.x * 256 + threadIdx.x;
  if (s < WSWN) {
    int j    = s & 7;
    int lane = (s >> 3) & 63;
    int ot   = (s >> 9) & 3;
    int ksg  = s >> 11;
    int o  = ot * 16 + (lane & 15);
    int kp = ksg * 32 + (lane >> 4) * 8 + j;   // padded-K index 0..2559
    int h  = kp / KPH;
    int kk = kp - h * KPH;
    int kb = kk >> 3, jo = kk & 7;
    int i, jb; kb_decode(kb, i, jb);
    int jch = jb * 8 + jo;
    float val = 0.f;
    if (jch >= i) {
      int fi = 32 * i - (i * (i - 1)) / 2;
      int m  = h * MT + fi + (jch - i);
      val = dr_w[(size_t)o * CP + m];
    }
    wsw[s] = f2bf(val);
  } else if (s < WSWN + FSWN) {
    int s2 = s - WSWN;
    int j    = s2 & 7;
    int lane = (s2 >> 3) & 63;
    int ot   = (s2 >> 9) & 3;
    int ks2  = s2 >> 11;
    int o = ot * 16 + (lane & 15);
    int c = ks2 * 32 + (lane >> 4) * 8 + j;
    fsw[s2] = f2bf(fc1_w[o * DIM_ + c]);
  }
}

// ---------------- k_w0: symmetric W matrices for the logit quadratic form ----------------
__global__ __launch_bounds__(256) void k_w0(const float* __restrict__ x,
                                            const float* __restrict__ g1,
                                            const float* __restrict__ b1,
                                            float* __restrict__ ws_w0) {
  int b = blockIdx.x;
  __shared__ float xs[CIN];
  __shared__ float tss[CIN];
  __shared__ float pm[CP];
  __shared__ float sqh[NH];
  __shared__ float musd[2];
  int t = threadIdx.x;
  if (t < CIN) xs[t] = x[(size_t)b * CIN * L_ + (size_t)t * L_ + MID];
  if (t < NH) sqh[t] = 0.f;
  __syncthreads();
  if (t == 0) {
    float s = 0.f;
    for (int c = 0; c < CIN; c++) s += xs[c];
    float mu = s / CIN;
    float s2 = 0.f;
    for (int c = 0; c < CIN; c++) { float d = xs[c] - mu; s2 += d * d; }
    musd[0] = mu; musd[1] = rsqrtf(s2 / CIN + EPS_);
  }
  __syncthreads();
  if (t < CIN) {
    int c = ((t & 31) << 2) + (t >> 5);   // shuffled row -> orig channel
    tss[t] = (xs[c] - musd[0]) * musd[1] * g1[c] + b1[c];
  }
  __syncthreads();
  for (int idx = t; idx < CP; idx += 256) {
    int h = idx / MT, m = idx - h * MT;
    int i = 0;
    while ((i + 1) * NN - ((i + 1) * i) / 2 <= m) i++;
    int j = i + (m - (i * NN - (i * (i - 1)) / 2));
    float p = tss[h * NN + i] * tss[h * NN + j];
    pm[idx] = p;
    atomicAdd(&sqh[h], p * p);
  }
  __syncthreads();
  // full symmetric W: W[i][j] = x0_ij (i==j) or x0_ij/2 (i!=j), x0 = pm/||pm_h||
  for (int idx = t; idx < NH * 1024; idx += 256) {
    int h = idx >> 10, r = idx & 1023;
    int i = r >> 5, j = r & 31;
    int ii = min(i, j), jj = max(i, j);
    int fi = 32 * ii - (ii * (ii - 1)) / 2;
    float w = pm[h * MT + fi + (jj - ii)] * rsqrtf(sqh[h]);
    ws_w0[(size_t)b * (NH * 1024) + idx] = (i == j) ? w : 0.5f * w;
  }
}

// ---------------- k_logits: t in regs, dp = t^T W t with wave-uniform W ----------------
__global__ __launch_bounds__(256) void k_logits(const float* __restrict__ x,
                                                const float* __restrict__ g1,
                                                const float* __restrict__ b1,
                                                const float* __restrict__ ws_w0,
                                                float* __restrict__ ws_a) {
  int blk = blockIdx.x;
  int b = blk >> 8;
  int l0 = (blk & 255) << 6;
  int t = threadIdx.x;
  int l = t & 63, q = t >> 6;
  __shared__ float part[4][64], part2[4][64], mu_s[64], isd_s[64];

  float tv[32];
  const float* xb = x + (size_t)b * CIN * L_ + l0 + l;
  float s = 0.f, s2 = 0.f;
#pragma unroll
  for (int cc = 0; cc < 32; cc++) {
    float v = xb[(size_t)(cc * 4 + q) * L_];
    tv[cc] = v; s += v; s2 += v * v;
  }
  part[q][l] = s; part2[q][l] = s2;
  __syncthreads();
  if (t < 64) {
    float su = part[0][t] + part[1][t] + part[2][t] + part[3][t];
    float su2 = part2[0][t] + part2[1][t] + part2[2][t] + part2[3][t];
    float mu = su * (1.f / CIN);
    float var = su2 * (1.f / CIN) - mu * mu;
    mu_s[t] = mu; isd_s[t] = rsqrtf(var + EPS_);
  }
  __syncthreads();
  {
    float mu = mu_s[l], isd = isd_s[l];
#pragma unroll
    for (int cc = 0; cc < 32; cc++) {
      int co = cc * 4 + q;
      tv[cc] = (tv[cc] - mu) * isd * g1[co] + b1[co];
    }
  }
  float S = 0.f, T4 = 0.f;
#pragma unroll
  for (int i = 0; i < 32; i++) { float t2 = tv[i] * tv[i]; S += t2; T4 = fmaf(t2, t2, T4); }
  int qu = __builtin_amdgcn_readfirstlane(q);
  const float* Wb = ws_w0 + ((size_t)b * NH + qu) * 1024;
  float dp = 0.f;
#pragma unroll 2
  for (int j = 0; j < 32; j++) {
    float rd = 0.f;
#pragma unroll
    for (int i = 0; i < 32; i++) rd = fmaf(Wb[j * 32 + i], tv[i], rd);
    dp = fmaf(tv[j], rd, dp);
  }
  float logit = dp * rsqrtf(0.5f * (S * S + T4));
  ws_a[((size_t)b * NH + q) * L_ + l0 + l] = logit;
}

// ---------------- k_softmax ----------------
__global__ __launch_bounds__(256) void k_softmax(const float* __restrict__ ws_a,
                                                 float* __restrict__ ws_stats) {
  int bh = blockIdx.x;
  const float* a = ws_a + (size_t)bh * L_;
  __shared__ float red[256];
  int t = threadIdx.x;
  float mx = -1e30f;
  for (int i = t; i < L_; i += 256) mx = fmaxf(mx, a[i]);
  red[t] = mx; __syncthreads();
  for (int s = 128; s > 0; s >>= 1) {
    if (t < s) red[t] = fmaxf(red[t], red[t + s]);
    __syncthreads();
  }
  float amax = red[0];
  __syncthreads();
  float sm = 0.f;
  for (int i = t; i < L_; i += 256) sm += expf(a[i] - amax);
  red[t] = sm; __syncthreads();
  for (int s = 128; s > 0; s >>= 1) {
    if (t < s) red[t] += red[t + s];
    __syncthreads();
  }
  if (t == 0) { ws_stats[bh * 2] = amax; ws_stats[bh * 2 + 1] = red[0]; }
}

// ---------------- kernel D: MFMA main (R3 verbatim, proven) ----------------
struct __align__(16) SmemM {
  union __align__(16) { unsigned short p2[4 * 5 * 4 * 16 * 8]; float zb[64 * 65]; } u1;
  union __align__(16) { unsigned short ut[64 * 128]; unsigned short zn2[4 * 2 * 4 * 16 * 8]; } u2;
  float part[4][64], part2[4][64], mu_s[64], isd_s[64];
};

__device__ inline int utidx(int l, int c) {
  return l * 128 + ((((c >> 3) ^ (l & 7))) << 3) + (c & 7);
}

__global__ __launch_bounds__(256, 3) void k_main(const float* __restrict__ x,
      const float* __restrict__ g1, const float* __restrict__ b1,
      const float* __restrict__ dr_b,
      const float* __restrict__ g2, const float* __restrict__ b2,
      const float* __restrict__ fc1_b,
      const unsigned short* __restrict__ wsw, const unsigned short* __restrict__ fsw,
      const float* __restrict__ ws_a, const float* __restrict__ ws_stats,
      float* __restrict__ out) {
  __shared__ SmemM sm;
  int blk = blockIdx.x;
  int b = blk >> 8;
  int l0 = (blk & 255) << 6;
  int t = threadIdx.x;
  int l = t & 63, q = t >> 6;   // q = wave id = l-tile; l = lane

  float amax = ws_stats[(b * NH + q) * 2];
  float asum = ws_stats[(b * NH + q) * 2 + 1];
  float av = ws_a[((size_t)b * NH + q) * L_ + l0 + l];
  float sa = sqrtf(expf(av - amax) * ((float)L_ / asum));

  const float* xb = x + (size_t)b * CIN * L_ + l0;
  float s = 0.f, s2 = 0.f;
#pragma unroll
  for (int cb = 0; cb < 4; cb++) {
    unsigned short pk[8];
#pragma unroll
    for (int e = 0; e < 8; e++) {
      int cc = cb * 8 + e;
      int co = cc * 4 + q;
      float v = xb[(size_t)co * L_ + l];
      s += v; s2 += v * v;
      pk[e] = f2bf(v);
    }
    *(short8*)&sm.u2.ut[l * 128 + (((q * 4 + cb) ^ (l & 7)) << 3)] = *(short8*)pk;
  }
  sm.part[q][l] = s; sm.part2[q][l] = s2;
  __syncthreads();
  if (t < 64) {
    float su = sm.part[0][t] + sm.part[1][t] + sm.part[2][t] + sm.part[3][t];
    float su2 = sm.part2[0][t] + sm.part2[1][t] + sm.part2[2][t] + sm.part2[3][t];
    float mu = su * (1.f / CIN);
    float var = su2 * (1.f / CIN) - mu * mu;
    sm.mu_s[t] = mu; sm.isd_s[t] = rsqrtf(var + EPS_);
  }
  __syncthreads();
  {
    float mu = sm.mu_s[l], isd = sm.isd_s[l];
#pragma unroll
    for (int cb = 0; cb < 4; cb++) {
      unsigned short* pp = &sm.u2.ut[l * 128 + (((q * 4 + cb) ^ (l & 7)) << 3)];
      short8 v8 = *(short8*)pp;
      unsigned short pk[8];
#pragma unroll
      for (int e = 0; e < 8; e++) {
        int cc = cb * 8 + e;
        int co = cc * 4 + q;
        float tvv = (bf2f((unsigned short)v8[e]) - mu) * isd * g1[co] + b1[co];
        pk[e] = f2bf(tvv * sa);
      }
      *(short8*)pp = *(short8*)pk;
    }
  }
  __syncthreads();

  float4v acc[4];
  acc[0] = (float4v)0.f; acc[1] = (float4v)0.f; acc[2] = (float4v)0.f; acc[3] = (float4v)0.f;
  int tl = l;
  int ltile = l >> 4, n = l & 15;

  for (int cc16 = 0; cc16 < 16; cc16++) {
    int h = cc16 >> 2;
    int cpart = cc16 & 3;
#pragma unroll
    for (int s5 = 0; s5 < 5; s5++) {
      int kbl = q * 5 + s5;            // 0..19
      int kbh = cpart * 20 + kbl;      // 0..79
      int i, jb; kb_decode(kbh, i, jb);
      float ui = bf2f(sm.u2.ut[utidx(l, h * 32 + i)]);
      short8 ub = *(short8*)&sm.u2.ut[l * 128 + (((h * 4 + jb) ^ (l & 7)) << 3)];
      unsigned short pk[8];
#pragma unroll
      for (int e = 0; e < 8; e++) pk[e] = f2bf(ui * bf2f((unsigned short)ub[e]));
      int ks = kbl >> 2, quad = kbl & 3;
      *(short8*)&sm.u1.p2[(((ltile * 5 + ks) * 4 + quad) * 16 + n) * 8] = *(short8*)pk;
    }
    __syncthreads();
    const unsigned short* wbase = wsw + (size_t)(cc16 * 5) * 2048 + tl * 8;
#pragma unroll
    for (int ks = 0; ks < 5; ks++) {
      short8 bf = *(short8*)&sm.u1.p2[((q * 5 + ks) * 64 + tl) * 8];
      const unsigned short* wk = wbase + ks * 2048;
      short8 a0 = *(const short8*)(wk);
      short8 a1 = *(const short8*)(wk + 512);
      short8 a2 = *(const short8*)(wk + 1024);
      short8 a3 = *(const short8*)(wk + 1536);
      acc[0] = __builtin_amdgcn_mfma_f32_16x16x32_bf16(a0, bf, acc[0], 0, 0, 0);
      acc[1] = __builtin_amdgcn_mfma_f32_16x16x32_bf16(a1, bf, acc[1], 0, 0, 0);
      acc[2] = __builtin_amdgcn_mfma_f32_16x16x32_bf16(a2, bf, acc[2], 0, 0, 0);
      acc[3] = __builtin_amdgcn_mfma_f32_16x16x32_bf16(a3, bf, acc[3], 0, 0, 0);
    }
    __syncthreads();
  }

  int quad = tl >> 4;
#pragma unroll
  for (int ot = 0; ot < 4; ot++) {
#pragma unroll
    for (int r = 0; r < 4; r++) {
      int o = ot * 16 + quad * 4 + r;
      sm.u1.zb[(q * 16 + n) * 65 + o] = acc[ot][r] + dr_b[o];
    }
  }
  __syncthreads();
  {
    float ss = 0.f, ss2 = 0.f;
#pragma unroll
    for (int k = 0; k < 16; k++) {
      float v = sm.u1.zb[l * 65 + q * 16 + k];
      ss += v; ss2 += v * v;
    }
    sm.part[q][l] = ss; sm.part2[q][l] = ss2;
  }
  __syncthreads();
  if (t < 64) {
    float su = sm.part[0][t] + sm.part[1][t] + sm.part[2][t] + sm.part[3][t];
    float su2 = sm.part2[0][t] + sm.part2[1][t] + sm.part2[2][t] + sm.part2[3][t];
    float mu = su * (1.f / DIM_);
    float var = su2 * (1.f / DIM_) - mu * mu;
    sm.mu_s[t] = mu; sm.isd_s[t] = rsqrtf(var + EPS_);
  }
  __syncthreads();
  {
    float mu2 = sm.mu_s[l], isd2 = sm.isd_s[l];
#pragma unroll
    for (int kk = 0; kk < 2; kk++) {
      int kb2 = q * 2 + kk;
      int c0 = kb2 * 8;
      unsigned short pk[8];
#pragma unroll
      for (int e = 0; e < 8; e++) {
        int c = c0 + e;
        float v = (sm.u1.zb[l * 65 + c] - mu2) * isd2 * g2[c] + b2[c];
        pk[e] = f2bf(v);
      }
      int ks2 = kb2 >> 2, qd2 = kb2 & 3;
      *(short8*)&sm.u2.zn2[(((ltile * 2 + ks2) * 4 + qd2) * 16 + n) * 8] = *(short8*)pk;
    }
  }
  __syncthreads();
  float4v acc2[4];
  acc2[0] = (float4v)0.f; acc2[1] = (float4v)0.f; acc2[2] = (float4v)0.f; acc2[3] = (float4v)0.f;
#pragma unroll
  for (int ks2 = 0; ks2 < 2; ks2++) {
    short8 bz = *(short8*)&sm.u2.zn2[((q * 2 + ks2) * 64 + tl) * 8];
    const unsigned short* fk = fsw + ks2 * 2048 + tl * 8;
    short8 f0 = *(const short8*)(fk);
    short8 f1 = *(const short8*)(fk + 512);
    short8 f2 = *(const short8*)(fk + 1024);
    short8 f3 = *(const short8*)(fk + 1536);
    acc2[0] = __builtin_amdgcn_mfma_f32_16x16x32_bf16(f0, bz, acc2[0], 0, 0, 0);
    acc2[1] = __builtin_amdgcn_mfma_f32_16x16x32_bf16(f1, bz, acc2[1], 0, 0, 0);
    acc2[2] = __builtin_amdgcn_mfma_f32_16x16x32_bf16(f2, bz, acc2[2], 0, 0, 0);
    acc2[3] = __builtin_amdgcn_mfma_f32_16x16x32_bf16(f3, bz, acc2[3], 0, 0, 0);
  }
#pragma unroll
  for (int ot = 0; ot < 4; ot++) {
#pragma unroll
    for (int r = 0; r < 4; r++) {
      int o2 = ot * 16 + quad * 4 + r;
      float sv = acc2[ot][r] + fc1_b[o2];
      float g = 0.5f * sv * (1.f + erff(sv * 0.70710678118f));
      out[((size_t)b * DIM_ + o2) * L_ + l0 + q * 16 + n] = g;
    }
  }
}

extern "C" void kernel_launch(void* const* d_in, const int* in_sizes, int n_in,
                              void* d_out, int out_size, void* d_ws, size_t ws_size,
                              hipStream_t stream) {
  const float* x    = (const float*)d_in[0];
  const float* n1w  = (const float*)d_in[1];
  const float* n1b  = (const float*)d_in[2];
  const float* drw  = (const float*)d_in[3];
  const float* drb  = (const float*)d_in[4];
  const float* n2w  = (const float*)d_in[5];
  const float* n2b  = (const float*)d_in[6];
  const float* fc1w = (const float*)d_in[7];
  const float* fc1b = (const float*)d_in[8];
  float* out = (float*)d_out;
  float* ws = (float*)d_ws;
  float* ws_w0 = ws;                                   // 4*4096 floats
  float* ws_a  = ws_w0 + B_ * NH * 1024;               // 4*4*16384 floats
  float* ws_st = ws_a + (size_t)B_ * NH * L_;          // 32 floats
  unsigned short* wsw = (unsigned short*)(ws_st + 32); // 163840 bf16
  unsigned short* fsw = wsw + WSWN;                    // 4096 bf16

  hipLaunchKernelGGL(k_prep, dim3((WSWN + FSWN) / 256), dim3(256), 0, stream, drw, fc1w, wsw, fsw);
  hipLaunchKernelGGL(k_w0, dim3(B_), dim3(256), 0, stream, x, n1w, n1b, ws_w0);
  hipLaunchKernelGGL(k_logits, dim3(B_ * (L_ / LT)), dim3(256), 0, stream,
                     x, n1w, n1b, ws_w0, ws_a);
  hipLaunchKernelGGL(k_softmax, dim3(B_ * NH), dim3(256), 0, stream, ws_a, ws_st);
  hipLaunchKernelGGL(k_main, dim3(B_ * (L_ / LT)), dim3(256), 0, stream,
                     x, n1w, n1b, drb, n2w, n2b, fc1b, wsw, fsw, ws_a, ws_st, out);
}

// Round 6
// 189.069 us; speedup vs baseline: 3.3546x; 1.0823x over previous
//
#include <hip/hip_runtime.h>
#include <hip/hip_bf16.h>
#include <math.h>

#define B_    4
#define CIN   128
#define L_    16384
#define NH    4
#define NN    32
#define MT    528
#define CP    2112
#define DIM_  64
#define LT    64
#define MID   8192
#define EPS_  1e-5f

// padded-K layout (R3-proven): per head 80 k-blocks of 8; heads contiguous in K.
#define KPH   640
#define KTOT  2560
#define WSWN  (KTOT * DIM_)       // 163840 bf16 slots
#define FSWN  (2 * 4 * 64 * 8)    // 4096 bf16 slots
#define PREP_BLOCKS 656           // (WSWN+FSWN)/256

typedef __attribute__((ext_vector_type(8))) short short8;
typedef __attribute__((ext_vector_type(4))) float float4v;

__device__ inline unsigned short f2bf(float f) {
  unsigned u = __float_as_uint(f);
  unsigned r = (u + 0x7fffu + ((u >> 16) & 1u)) >> 16;
  return (unsigned short)r;
}
__device__ inline float bf2f(unsigned short h) {
  return __uint_as_float(((unsigned)h) << 16);
}

// decode head-local k-block (0..79) -> (i, jb)
__device__ inline void kb_decode(int id, int& i, int& jb) {
  if (id < 32)      { i = id >> 2;               jb = id & 3; }
  else if (id < 56) { int r = id - 32; int d = r / 3; i = 8 + d;  jb = 1 + (r - 3 * d); }
  else if (id < 72) { int r = id - 56; i = 16 + (r >> 1); jb = 2 + (r & 1); }
  else              { i = 24 + (id - 72);         jb = 3; }
}

// ---------------- fused prep (weight swizzle) + w0 (logit quadratic form) ----------------
__global__ __launch_bounds__(256) void k_prep_w0(const float* __restrict__ dr_w,
                                                 const float* __restrict__ fc1_w,
                                                 const float* __restrict__ x,
                                                 const float* __restrict__ g1,
                                                 const float* __restrict__ b1,
                                                 unsigned short* __restrict__ wsw,
                                                 unsigned short* __restrict__ fsw,
                                                 float* __restrict__ ws_w0) {
  if (blockIdx.x < PREP_BLOCKS) {
    int s = blockIdx.x * 256 + threadIdx.x;
    if (s < WSWN) {
      int j    = s & 7;
      int lane = (s >> 3) & 63;
      int ot   = (s >> 9) & 3;
      int ksg  = s >> 11;
      int o  = ot * 16 + (lane & 15);
      int kp = ksg * 32 + (lane >> 4) * 8 + j;   // padded-K index 0..2559
      int h  = kp / KPH;
      int kk = kp - h * KPH;
      int kb = kk >> 3, jo = kk & 7;
      int i, jb; kb_decode(kb, i, jb);
      int jch = jb * 8 + jo;
      float val = 0.f;
      if (jch >= i) {
        int fi = 32 * i - (i * (i - 1)) / 2;
        int m  = h * MT + fi + (jch - i);
        val = dr_w[(size_t)o * CP + m];
      }
      wsw[s] = f2bf(val);
    } else {
      int s2 = s - WSWN;
      int j    = s2 & 7;
      int lane = (s2 >> 3) & 63;
      int ot   = (s2 >> 9) & 3;
      int ks2  = s2 >> 11;
      int o = ot * 16 + (lane & 15);
      int c = ks2 * 32 + (lane >> 4) * 8 + j;
      fsw[s2] = f2bf(fc1_w[o * DIM_ + c]);
    }
    return;
  }
  // ---- w0 path: one block per batch ----
  int b = blockIdx.x - PREP_BLOCKS;
  __shared__ float xs[CIN];
  __shared__ float tss[CIN];
  __shared__ float pm[CP];
  __shared__ float sqh[NH];
  __shared__ float musd[2];
  int t = threadIdx.x;
  if (t < CIN) xs[t] = x[(size_t)b * CIN * L_ + (size_t)t * L_ + MID];
  if (t < NH) sqh[t] = 0.f;
  __syncthreads();
  if (t == 0) {
    float s = 0.f;
    for (int c = 0; c < CIN; c++) s += xs[c];
    float mu = s / CIN;
    float s2 = 0.f;
    for (int c = 0; c < CIN; c++) { float d = xs[c] - mu; s2 += d * d; }
    musd[0] = mu; musd[1] = rsqrtf(s2 / CIN + EPS_);
  }
  __syncthreads();
  if (t < CIN) {
    int c = ((t & 31) << 2) + (t >> 5);   // shuffled row -> orig channel
    tss[t] = (xs[c] - musd[0]) * musd[1] * g1[c] + b1[c];
  }
  __syncthreads();
  for (int idx = t; idx < CP; idx += 256) {
    int h = idx / MT, m = idx - h * MT;
    int i = 0;
    while ((i + 1) * NN - ((i + 1) * i) / 2 <= m) i++;
    int j = i + (m - (i * NN - (i * (i - 1)) / 2));
    float p = tss[h * NN + i] * tss[h * NN + j];
    pm[idx] = p;
    atomicAdd(&sqh[h], p * p);
  }
  __syncthreads();
  // full symmetric W: W[i][j] = x0_ij (i==j) or x0_ij/2 (i!=j), x0 = pm/||pm_h||
  for (int idx = t; idx < NH * 1024; idx += 256) {
    int h = idx >> 10, r = idx & 1023;
    int i = r >> 5, j = r & 31;
    int ii = min(i, j), jj = max(i, j);
    int fi = 32 * ii - (ii * (ii - 1)) / 2;
    float w = pm[h * MT + fi + (jj - ii)] * rsqrtf(sqh[h]);
    ws_w0[(size_t)b * (NH * 1024) + idx] = (i == j) ? w : 0.5f * w;
  }
}

// ---------------- k_logits: e = exp(logit-1) + deterministic per-block head sums ----------------
// logit = <x0, p>/||p|| with ||x0||=1  =>  logit in [-1,1]; max is exactly 1 at l=MID.
__global__ __launch_bounds__(256) void k_logits(const float* __restrict__ x,
                                                const float* __restrict__ g1,
                                                const float* __restrict__ b1,
                                                const float* __restrict__ ws_w0,
                                                float* __restrict__ ws_a,
                                                float* __restrict__ ws_bsum) {
  int blk = blockIdx.x;
  int b = blk >> 8;
  int l0 = (blk & 255) << 6;
  int t = threadIdx.x;
  int l = t & 63, q = t >> 6;
  __shared__ float part[4][64], part2[4][64], mu_s[64], isd_s[64];

  float tv[32];
  const float* xb = x + (size_t)b * CIN * L_ + l0 + l;
  float s = 0.f, s2 = 0.f;
#pragma unroll
  for (int cc = 0; cc < 32; cc++) {
    float v = xb[(size_t)(cc * 4 + q) * L_];
    tv[cc] = v; s += v; s2 += v * v;
  }
  part[q][l] = s; part2[q][l] = s2;
  __syncthreads();
  if (t < 64) {
    float su = part[0][t] + part[1][t] + part[2][t] + part[3][t];
    float su2 = part2[0][t] + part2[1][t] + part2[2][t] + part2[3][t];
    float mu = su * (1.f / CIN);
    float var = su2 * (1.f / CIN) - mu * mu;
    mu_s[t] = mu; isd_s[t] = rsqrtf(var + EPS_);
  }
  __syncthreads();
  {
    float mu = mu_s[l], isd = isd_s[l];
#pragma unroll
    for (int cc = 0; cc < 32; cc++) {
      int co = cc * 4 + q;
      tv[cc] = (tv[cc] - mu) * isd * g1[co] + b1[co];
    }
  }
  float S = 0.f, T4 = 0.f;
#pragma unroll
  for (int i = 0; i < 32; i++) { float t2 = tv[i] * tv[i]; S += t2; T4 = fmaf(t2, t2, T4); }
  int qu = __builtin_amdgcn_readfirstlane(q);
  const float* Wb = ws_w0 + ((size_t)b * NH + qu) * 1024;
  float dp = 0.f;
#pragma unroll 2
  for (int j = 0; j < 32; j++) {
    float rd = 0.f;
#pragma unroll
    for (int i = 0; i < 32; i++) rd = fmaf(Wb[j * 32 + i], tv[i], rd);
    dp = fmaf(tv[j], rd, dp);
  }
  float logit = dp * rsqrtf(0.5f * (S * S + T4));
  float e = expf(logit - 1.f);
  ws_a[((size_t)b * NH + q) * L_ + l0 + l] = e;
  // wave-level butterfly sum of e over 64 lanes -> one partial per (block, head)
  float ws = e;
#pragma unroll
  for (int mk = 1; mk < 64; mk <<= 1) ws += __shfl_xor(ws, mk, 64);
  if (l == 0) ws_bsum[((size_t)b * NH + q) * 256 + (blk & 255)] = ws;
}

// ---------------- kernel D: MFMA main (R3/R5 verbatim except softmax-stat read) ----------------
struct __align__(16) SmemM {
  union __align__(16) { unsigned short p2[4 * 5 * 4 * 16 * 8]; float zb[64 * 65]; } u1;
  union __align__(16) { unsigned short ut[64 * 128]; unsigned short zn2[4 * 2 * 4 * 16 * 8]; } u2;
  float part[4][64], part2[4][64], mu_s[64], isd_s[64];
};

__device__ inline int utidx(int l, int c) {
  return l * 128 + ((((c >> 3) ^ (l & 7))) << 3) + (c & 7);
}

__global__ __launch_bounds__(256, 3) void k_main(const float* __restrict__ x,
      const float* __restrict__ g1, const float* __restrict__ b1,
      const float* __restrict__ dr_b,
      const float* __restrict__ g2, const float* __restrict__ b2,
      const float* __restrict__ fc1_b,
      const unsigned short* __restrict__ wsw, const unsigned short* __restrict__ fsw,
      const float* __restrict__ ws_a, const float* __restrict__ ws_bsum,
      float* __restrict__ out) {
  __shared__ SmemM sm;
  int blk = blockIdx.x;
  int b = blk >> 8;
  int l0 = (blk & 255) << 6;
  int t = threadIdx.x;
  int l = t & 63, q = t >> 6;   // q = wave id = l-tile; l = lane

  // attn = e * L / sum(e); fold sqrt(attn) into u
  float asum;
  {
    const float* bs = ws_bsum + ((size_t)b * NH + q) * 256;
    float a0 = 0.f;
    for (int i = 0; i < 256; i++) a0 += bs[i];   // wave-uniform scalar loads
    asum = a0;
  }
  float e = ws_a[((size_t)b * NH + q) * L_ + l0 + l];
  float sa = sqrtf(e * ((float)L_ / asum));

  const float* xb = x + (size_t)b * CIN * L_ + l0;
  float s = 0.f, s2 = 0.f;
#pragma unroll
  for (int cb = 0; cb < 4; cb++) {
    unsigned short pk[8];
#pragma unroll
    for (int e8 = 0; e8 < 8; e8++) {
      int cc = cb * 8 + e8;
      int co = cc * 4 + q;
      float v = xb[(size_t)co * L_ + l];
      s += v; s2 += v * v;
      pk[e8] = f2bf(v);
    }
    *(short8*)&sm.u2.ut[l * 128 + (((q * 4 + cb) ^ (l & 7)) << 3)] = *(short8*)pk;
  }
  sm.part[q][l] = s; sm.part2[q][l] = s2;
  __syncthreads();
  if (t < 64) {
    float su = sm.part[0][t] + sm.part[1][t] + sm.part[2][t] + sm.part[3][t];
    float su2 = sm.part2[0][t] + sm.part2[1][t] + sm.part2[2][t] + sm.part2[3][t];
    float mu = su * (1.f / CIN);
    float var = su2 * (1.f / CIN) - mu * mu;
    sm.mu_s[t] = mu; sm.isd_s[t] = rsqrtf(var + EPS_);
  }
  __syncthreads();
  {
    float mu = sm.mu_s[l], isd = sm.isd_s[l];
#pragma unroll
    for (int cb = 0; cb < 4; cb++) {
      unsigned short* pp = &sm.u2.ut[l * 128 + (((q * 4 + cb) ^ (l & 7)) << 3)];
      short8 v8 = *(short8*)pp;
      unsigned short pk[8];
#pragma unroll
      for (int e8 = 0; e8 < 8; e8++) {
        int cc = cb * 8 + e8;
        int co = cc * 4 + q;
        float tvv = (bf2f((unsigned short)v8[e8]) - mu) * isd * g1[co] + b1[co];
        pk[e8] = f2bf(tvv * sa);
      }
      *(short8*)pp = *(short8*)pk;
    }
  }
  __syncthreads();

  float4v acc[4];
  acc[0] = (float4v)0.f; acc[1] = (float4v)0.f; acc[2] = (float4v)0.f; acc[3] = (float4v)0.f;
  int tl = l;
  int ltile = l >> 4, n = l & 15;

  for (int cc16 = 0; cc16 < 16; cc16++) {
    int h = cc16 >> 2;
    int cpart = cc16 & 3;
#pragma unroll
    for (int s5 = 0; s5 < 5; s5++) {
      int kbl = q * 5 + s5;            // 0..19
      int kbh = cpart * 20 + kbl;      // 0..79
      int i, jb; kb_decode(kbh, i, jb);
      float ui = bf2f(sm.u2.ut[utidx(l, h * 32 + i)]);
      short8 ub = *(short8*)&sm.u2.ut[l * 128 + (((h * 4 + jb) ^ (l & 7)) << 3)];
      unsigned short pk[8];
#pragma unroll
      for (int e8 = 0; e8 < 8; e8++) pk[e8] = f2bf(ui * bf2f((unsigned short)ub[e8]));
      int ks = kbl >> 2, quad = kbl & 3;
      *(short8*)&sm.u1.p2[(((ltile * 5 + ks) * 4 + quad) * 16 + n) * 8] = *(short8*)pk;
    }
    __syncthreads();
    const unsigned short* wbase = wsw + (size_t)(cc16 * 5) * 2048 + tl * 8;
#pragma unroll
    for (int ks = 0; ks < 5; ks++) {
      short8 bf = *(short8*)&sm.u1.p2[((q * 5 + ks) * 64 + tl) * 8];
      const unsigned short* wk = wbase + ks * 2048;
      short8 a0 = *(const short8*)(wk);
      short8 a1 = *(const short8*)(wk + 512);
      short8 a2 = *(const short8*)(wk + 1024);
      short8 a3 = *(const short8*)(wk + 1536);
      acc[0] = __builtin_amdgcn_mfma_f32_16x16x32_bf16(a0, bf, acc[0], 0, 0, 0);
      acc[1] = __builtin_amdgcn_mfma_f32_16x16x32_bf16(a1, bf, acc[1], 0, 0, 0);
      acc[2] = __builtin_amdgcn_mfma_f32_16x16x32_bf16(a2, bf, acc[2], 0, 0, 0);
      acc[3] = __builtin_amdgcn_mfma_f32_16x16x32_bf16(a3, bf, acc[3], 0, 0, 0);
    }
    __syncthreads();
  }

  int quad = tl >> 4;
#pragma unroll
  for (int ot = 0; ot < 4; ot++) {
#pragma unroll
    for (int r = 0; r < 4; r++) {
      int o = ot * 16 + quad * 4 + r;
      sm.u1.zb[(q * 16 + n) * 65 + o] = acc[ot][r] + dr_b[o];
    }
  }
  __syncthreads();
  {
    float ss = 0.f, ss2 = 0.f;
#pragma unroll
    for (int k = 0; k < 16; k++) {
      float v = sm.u1.zb[l * 65 + q * 16 + k];
      ss += v; ss2 += v * v;
    }
    sm.part[q][l] = ss; sm.part2[q][l] = ss2;
  }
  __syncthreads();
  if (t < 64) {
    float su = sm.part[0][t] + sm.part[1][t] + sm.part[2][t] + sm.part[3][t];
    float su2 = sm.part2[0][t] + sm.part2[1][t] + sm.part2[2][t] + sm.part2[3][t];
    float mu = su * (1.f / DIM_);
    float var = su2 * (1.f / DIM_) - mu * mu;
    sm.mu_s[t] = mu; sm.isd_s[t] = rsqrtf(var + EPS_);
  }
  __syncthreads();
  {
    float mu2 = sm.mu_s[l], isd2 = sm.isd_s[l];
#pragma unroll
    for (int kk = 0; kk < 2; kk++) {
      int kb2 = q * 2 + kk;
      int c0 = kb2 * 8;
      unsigned short pk[8];
#pragma unroll
      for (int e8 = 0; e8 < 8; e8++) {
        int c = c0 + e8;
        float v = (sm.u1.zb[l * 65 + c] - mu2) * isd2 * g2[c] + b2[c];
        pk[e8] = f2bf(v);
      }
      int ks2 = kb2 >> 2, qd2 = kb2 & 3;
      *(short8*)&sm.u2.zn2[(((ltile * 2 + ks2) * 4 + qd2) * 16 + n) * 8] = *(short8*)pk;
    }
  }
  __syncthreads();
  float4v acc2[4];
  acc2[0] = (float4v)0.f; acc2[1] = (float4v)0.f; acc2[2] = (float4v)0.f; acc2[3] = (float4v)0.f;
#pragma unroll
  for (int ks2 = 0; ks2 < 2; ks2++) {
    short8 bz = *(short8*)&sm.u2.zn2[((q * 2 + ks2) * 64 + tl) * 8];
    const unsigned short* fk = fsw + ks2 * 2048 + tl * 8;
    short8 f0 = *(const short8*)(fk);
    short8 f1 = *(const short8*)(fk + 512);
    short8 f2 = *(const short8*)(fk + 1024);
    short8 f3 = *(const short8*)(fk + 1536);
    acc2[0] = __builtin_amdgcn_mfma_f32_16x16x32_bf16(f0, bz, acc2[0], 0, 0, 0);
    acc2[1] = __builtin_amdgcn_mfma_f32_16x16x32_bf16(f1, bz, acc2[1], 0, 0, 0);
    acc2[2] = __builtin_amdgcn_mfma_f32_16x16x32_bf16(f2, bz, acc2[2], 0, 0, 0);
    acc2[3] = __builtin_amdgcn_mfma_f32_16x16x32_bf16(f3, bz, acc2[3], 0, 0, 0);
  }
#pragma unroll
  for (int ot = 0; ot < 4; ot++) {
#pragma unroll
    for (int r = 0; r < 4; r++) {
      int o2 = ot * 16 + quad * 4 + r;
      float sv = acc2[ot][r] + fc1_b[o2];
      float g = 0.5f * sv * (1.f + erff(sv * 0.70710678118f));
      out[((size_t)b * DIM_ + o2) * L_ + l0 + q * 16 + n] = g;
    }
  }
}

extern "C" void kernel_launch(void* const* d_in, const int* in_sizes, int n_in,
                              void* d_out, int out_size, void* d_ws, size_t ws_size,
                              hipStream_t stream) {
  const float* x    = (const float*)d_in[0];
  const float* n1w  = (const float*)d_in[1];
  const float* n1b  = (const float*)d_in[2];
  const float* drw  = (const float*)d_in[3];
  const float* drb  = (const float*)d_in[4];
  const float* n2w  = (const float*)d_in[5];
  const float* n2b  = (const float*)d_in[6];
  const float* fc1w = (const float*)d_in[7];
  const float* fc1b = (const float*)d_in[8];
  float* out = (float*)d_out;
  float* ws = (float*)d_ws;
  float* ws_w0   = ws;                                  // 4*4096 floats
  float* ws_a    = ws_w0 + B_ * NH * 1024;              // 4*4*16384 floats
  float* ws_bsum = ws_a + (size_t)B_ * NH * L_;         // 16*256 floats
  unsigned short* wsw = (unsigned short*)(ws_bsum + B_ * NH * 256); // 163840 bf16
  unsigned short* fsw = wsw + WSWN;                     // 4096 bf16

  hipLaunchKernelGGL(k_prep_w0, dim3(PREP_BLOCKS + B_), dim3(256), 0, stream,
                     drw, fc1w, x, n1w, n1b, wsw, fsw, ws_w0);
  hipLaunchKernelGGL(k_logits, dim3(B_ * (L_ / LT)), dim3(256), 0, stream,
                     x, n1w, n1b, ws_w0, ws_a, ws_bsum);
  hipLaunchKernelGGL(k_main, dim3(B_ * (L_ / LT)), dim3(256), 0, stream,
                     x, n1w, n1b, drb, n2w, n2b, fc1b, wsw, fsw, ws_a, ws_bsum, out);
}

// Round 7
// 152.203 us; speedup vs baseline: 4.1672x; 1.2422x over previous
//
#include <hip/hip_runtime.h>
#include <hip/hip_bf16.h>
#include <math.h>

#define B_    4
#define CIN   128
#define L_    16384
#define NH    4
#define NN    32
#define MT    528
#define CP    2112
#define DIM_  64
#define LT    64
#define MID   8192
#define EPS_  1e-5f

// padded-K layout (R3-proven): per head 80 k-blocks of 8; heads contiguous in K.
#define KPH   640
#define KTOT  2560
#define WSWN  (KTOT * DIM_)       // 163840 bf16 slots
#define FSWN  (2 * 4 * 64 * 8)    // 4096 bf16 slots
#define LOGITS_BLOCKS 1024
#define PREP_BLOCKS   656         // (WSWN+FSWN)/256

typedef __attribute__((ext_vector_type(8))) short short8;
typedef __attribute__((ext_vector_type(4))) float float4v;

__device__ inline unsigned short f2bf(float f) {
  unsigned u = __float_as_uint(f);
  unsigned r = (u + 0x7fffu + ((u >> 16) & 1u)) >> 16;
  return (unsigned short)r;
}
__device__ inline float bf2f(unsigned short h) {
  return __uint_as_float(((unsigned)h) << 16);
}

// decode head-local k-block (0..79) -> (i, jb)
__device__ inline void kb_decode(int id, int& i, int& jb) {
  if (id < 32)      { i = id >> 2;               jb = id & 3; }
  else if (id < 56) { int r = id - 32; int d = r / 3; i = 8 + d;  jb = 1 + (r - 3 * d); }
  else if (id < 72) { int r = id - 56; i = 16 + (r >> 1); jb = 2 + (r & 1); }
  else              { i = 24 + (id - 72);         jb = 3; }
}

// ---------------- kernel 1: logits (closed-form, self-contained) ∪ weight-swizzle prep ----------------
// logit = <x0,p>/||p||, x0 = p0/||p0||, p0 = outer(s,s) triu, p = outer(t,t) triu:
//   <p0,p>  = 0.5*((s.t)^2 + sum_i (s_i t_i)^2)
//   ||p0||^2= 0.5*((sum s^2)^2 + sum s^4),  ||p||^2 = 0.5*((sum t^2)^2 + sum t^4)
// e = exp(logit - 1) (shift-invariant softmax; logit<=1 by Cauchy-Schwarz).
__global__ __launch_bounds__(256) void k_pre(const float* __restrict__ dr_w,
                                             const float* __restrict__ fc1_w,
                                             const float* __restrict__ x,
                                             const float* __restrict__ g1,
                                             const float* __restrict__ b1,
                                             unsigned short* __restrict__ wsw,
                                             unsigned short* __restrict__ fsw,
                                             float* __restrict__ ws_a,
                                             float* __restrict__ ws_bsum) {
  if (blockIdx.x >= LOGITS_BLOCKS) {
    // ---- prep path: swizzle dr_w / fc1_w into MFMA A-frag order (R3-proven mapping) ----
    int s = (blockIdx.x - LOGITS_BLOCKS) * 256 + threadIdx.x;
    if (s < WSWN) {
      int j    = s & 7;
      int lane = (s >> 3) & 63;
      int ot   = (s >> 9) & 3;
      int ksg  = s >> 11;
      int o  = ot * 16 + (lane & 15);
      int kp = ksg * 32 + (lane >> 4) * 8 + j;   // padded-K index 0..2559
      int h  = kp / KPH;
      int kk = kp - h * KPH;
      int kb = kk >> 3, jo = kk & 7;
      int i, jb; kb_decode(kb, i, jb);
      int jch = jb * 8 + jo;
      float val = 0.f;
      if (jch >= i) {
        int fi = 32 * i - (i * (i - 1)) / 2;
        int m  = h * MT + fi + (jch - i);
        val = dr_w[(size_t)o * CP + m];
      }
      wsw[s] = f2bf(val);
    } else {
      int s2 = s - WSWN;
      int j    = s2 & 7;
      int lane = (s2 >> 3) & 63;
      int ot   = (s2 >> 9) & 3;
      int ks2  = s2 >> 11;
      int o = ot * 16 + (lane & 15);
      int c = ks2 * 32 + (lane >> 4) * 8 + j;
      fsw[s2] = f2bf(fc1_w[o * DIM_ + c]);
    }
    return;
  }
  // ---- logits path ----
  int blk = blockIdx.x;
  int b = blk >> 8;
  int l0 = (blk & 255) << 6;
  int t = threadIdx.x;
  int l = t & 63, q = t >> 6;
  __shared__ float xs[CIN], smid[CIN];
  __shared__ float part[4][64], part2[4][64], mu_s[64], isd_s[64];
  __shared__ float musd[2];

  if (t < CIN) xs[t] = x[(size_t)b * CIN * L_ + (size_t)t * L_ + MID];

  float tv[32];
  const float* xb = x + (size_t)b * CIN * L_ + l0 + l;
  float s = 0.f, s2 = 0.f;
#pragma unroll
  for (int cc = 0; cc < 32; cc++) {
    float v = xb[(size_t)(cc * 4 + q) * L_];
    tv[cc] = v; s += v; s2 += v * v;
  }
  part[q][l] = s; part2[q][l] = s2;
  __syncthreads();
  if (t == 0) {
    float su = 0.f;
    for (int c = 0; c < CIN; c++) su += xs[c];
    float mu = su / CIN;
    float sv = 0.f;
    for (int c = 0; c < CIN; c++) { float d = xs[c] - mu; sv += d * d; }
    musd[0] = mu; musd[1] = rsqrtf(sv / CIN + EPS_);
  }
  if (t < 64) {
    float su = part[0][t] + part[1][t] + part[2][t] + part[3][t];
    float su2 = part2[0][t] + part2[1][t] + part2[2][t] + part2[3][t];
    float mu = su * (1.f / CIN);
    float var = su2 * (1.f / CIN) - mu * mu;
    mu_s[t] = mu; isd_s[t] = rsqrtf(var + EPS_);
  }
  __syncthreads();
  if (t < CIN) {
    int c = ((t & 31) << 2) + (t >> 5);   // shuffled row -> orig channel
    smid[t] = (xs[c] - musd[0]) * musd[1] * g1[c] + b1[c];
  }
  {
    float mu = mu_s[l], isd = isd_s[l];
#pragma unroll
    for (int cc = 0; cc < 32; cc++) {
      int co = cc * 4 + q;
      tv[cc] = (tv[cc] - mu) * isd * g1[co] + b1[co];
    }
  }
  __syncthreads();
  // closed-form logit
  float T2 = 0.f, T4 = 0.f, st = 0.f, sc2 = 0.f, S2 = 0.f, S4 = 0.f;
#pragma unroll
  for (int i = 0; i < 32; i++) {
    float si = smid[q * 32 + i];           // wave-uniform broadcast read
    float ti = tv[i];
    float t2 = ti * ti;
    T2 += t2; T4 = fmaf(t2, t2, T4);
    float ci = si * ti;
    st += ci; sc2 = fmaf(ci, ci, sc2);
    float s2i = si * si;
    S2 += s2i; S4 = fmaf(s2i, s2i, S4);
  }
  float num = 0.5f * (st * st + sc2);
  float logit = num * rsqrtf(0.25f * (T2 * T2 + T4) * (S2 * S2 + S4));
  float e = expf(logit - 1.f);
  ws_a[((size_t)b * NH + q) * L_ + l0 + l] = e;
  float ws = e;
#pragma unroll
  for (int mk = 1; mk < 64; mk <<= 1) ws += __shfl_xor(ws, mk, 64);
  if (l == 0) ws_bsum[((size_t)b * NH + q) * 256 + (blk & 255)] = ws;
}

// ---------------- kernel 2: MFMA main (R5 core; 2x2-tiled consume; parallel asum) ----------------
struct __align__(16) SmemM {
  union __align__(16) { unsigned short p2[4 * 5 * 4 * 16 * 8]; float zb[64 * 65]; } u1;
  union __align__(16) { unsigned short ut[64 * 128]; unsigned short zn2[4 * 2 * 4 * 16 * 8]; } u2;
  float part[4][64], part2[4][64], mu_s[64], isd_s[64];
};

__device__ inline int utidx(int l, int c) {
  return l * 128 + ((((c >> 3) ^ (l & 7))) << 3) + (c & 7);
}

__global__ __launch_bounds__(256, 3) void k_main(const float* __restrict__ x,
      const float* __restrict__ g1, const float* __restrict__ b1,
      const float* __restrict__ dr_b,
      const float* __restrict__ g2, const float* __restrict__ b2,
      const float* __restrict__ fc1_b,
      const unsigned short* __restrict__ wsw, const unsigned short* __restrict__ fsw,
      const float* __restrict__ ws_a, const float* __restrict__ ws_bsum,
      float* __restrict__ out) {
  __shared__ SmemM sm;
  int blk = blockIdx.x;
  int b = blk >> 8;
  int l0 = (blk & 255) << 6;
  int t = threadIdx.x;
  int l = t & 63, q = t >> 6;   // staging/P-build: position l, head q

  // asum: parallel 256-partial read + wave butterfly (deterministic)
  float asum;
  {
    const float* bs = ws_bsum + ((size_t)b * NH + q) * 256;
    float a0 = bs[l] + bs[l + 64] + bs[l + 128] + bs[l + 192];
#pragma unroll
    for (int mk = 1; mk < 64; mk <<= 1) a0 += __shfl_xor(a0, mk, 64);
    asum = a0;
  }
  float e = ws_a[((size_t)b * NH + q) * L_ + l0 + l];
  float sa = sqrtf(e * ((float)L_ / asum));

  const float* xb = x + (size_t)b * CIN * L_ + l0;
  float s = 0.f, s2 = 0.f;
#pragma unroll
  for (int cb = 0; cb < 4; cb++) {
    unsigned short pk[8];
#pragma unroll
    for (int e8 = 0; e8 < 8; e8++) {
      int cc = cb * 8 + e8;
      int co = cc * 4 + q;
      float v = xb[(size_t)co * L_ + l];
      s += v; s2 += v * v;
      pk[e8] = f2bf(v);
    }
    *(short8*)&sm.u2.ut[l * 128 + (((q * 4 + cb) ^ (l & 7)) << 3)] = *(short8*)pk;
  }
  sm.part[q][l] = s; sm.part2[q][l] = s2;
  __syncthreads();
  if (t < 64) {
    float su = sm.part[0][t] + sm.part[1][t] + sm.part[2][t] + sm.part[3][t];
    float su2 = sm.part2[0][t] + sm.part2[1][t] + sm.part2[2][t] + sm.part2[3][t];
    float mu = su * (1.f / CIN);
    float var = su2 * (1.f / CIN) - mu * mu;
    sm.mu_s[t] = mu; sm.isd_s[t] = rsqrtf(var + EPS_);
  }
  __syncthreads();
  {
    float mu = sm.mu_s[l], isd = sm.isd_s[l];
#pragma unroll
    for (int cb = 0; cb < 4; cb++) {
      unsigned short* pp = &sm.u2.ut[l * 128 + (((q * 4 + cb) ^ (l & 7)) << 3)];
      short8 v8 = *(short8*)pp;
      unsigned short pk[8];
#pragma unroll
      for (int e8 = 0; e8 < 8; e8++) {
        int cc = cb * 8 + e8;
        int co = cc * 4 + q;
        float tvv = (bf2f((unsigned short)v8[e8]) - mu) * isd * g1[co] + b1[co];
        pk[e8] = f2bf(tvv * sa);
      }
      *(short8*)pp = *(short8*)pk;
    }
  }
  __syncthreads();

  // main GEMM: wave q owns otile-pair (q&1) x ltile-pair (q>>1)
  const int otp = q & 1, ltp = q >> 1;
  const int lta = ltp * 2, ltb = ltp * 2 + 1;
  float4v acc[2][2];
  acc[0][0] = (float4v)0.f; acc[0][1] = (float4v)0.f;
  acc[1][0] = (float4v)0.f; acc[1][1] = (float4v)0.f;
  int tl = l;
  int ltile = l >> 4, n = l & 15;

  for (int cc16 = 0; cc16 < 16; cc16++) {
    int h = cc16 >> 2;
    int cpart = cc16 & 3;
    // P-build (unchanged from R5): thread (l,q) builds head-q local k-blocks
#pragma unroll
    for (int s5 = 0; s5 < 5; s5++) {
      int kbl = q * 5 + s5;            // 0..19
      int kbh = cpart * 20 + kbl;      // 0..79
      int i, jb; kb_decode(kbh, i, jb);
      float ui = bf2f(sm.u2.ut[utidx(l, h * 32 + i)]);
      short8 ub = *(short8*)&sm.u2.ut[l * 128 + (((h * 4 + jb) ^ (l & 7)) << 3)];
      unsigned short pk[8];
#pragma unroll
      for (int e8 = 0; e8 < 8; e8++) pk[e8] = f2bf(ui * bf2f((unsigned short)ub[e8]));
      int ks = kbl >> 2, quad = kbl & 3;
      *(short8*)&sm.u1.p2[(((ltile * 5 + ks) * 4 + quad) * 16 + n) * 8] = *(short8*)pk;
    }
    __syncthreads();
    // consume: 2 otiles x 2 ltiles per wave (halves redundant A traffic)
#pragma unroll
    for (int ks = 0; ks < 5; ks++) {
      const unsigned short* wk = wsw + (size_t)(cc16 * 5 + ks) * 2048 + otp * 1024 + tl * 8;
      short8 a0 = *(const short8*)(wk);
      short8 a1 = *(const short8*)(wk + 512);
      short8 b0 = *(short8*)&sm.u1.p2[((lta * 5 + ks) * 64 + tl) * 8];
      short8 b1v = *(short8*)&sm.u1.p2[((ltb * 5 + ks) * 64 + tl) * 8];
      acc[0][0] = __builtin_amdgcn_mfma_f32_16x16x32_bf16(a0, b0,  acc[0][0], 0, 0, 0);
      acc[0][1] = __builtin_amdgcn_mfma_f32_16x16x32_bf16(a0, b1v, acc[0][1], 0, 0, 0);
      acc[1][0] = __builtin_amdgcn_mfma_f32_16x16x32_bf16(a1, b0,  acc[1][0], 0, 0, 0);
      acc[1][1] = __builtin_amdgcn_mfma_f32_16x16x32_bf16(a1, b1v, acc[1][1], 0, 0, 0);
    }
    __syncthreads();
  }

  // epilogue: z -> zb (2x2 mapping), norm2, zn2 frags, fc1 MFMA (R5 verbatim), GELU
  int quad = tl >> 4;
#pragma unroll
  for (int oi = 0; oi < 2; oi++) {
#pragma unroll
    for (int li = 0; li < 2; li++) {
      int ot = otp * 2 + oi, ltx = ltp * 2 + li;
#pragma unroll
      for (int r = 0; r < 4; r++) {
        int o = ot * 16 + quad * 4 + r;
        sm.u1.zb[(ltx * 16 + n) * 65 + o] = acc[oi][li][r] + dr_b[o];
      }
    }
  }
  __syncthreads();
  {
    float ss = 0.f, ss2 = 0.f;
#pragma unroll
    for (int k = 0; k < 16; k++) {
      float v = sm.u1.zb[l * 65 + q * 16 + k];
      ss += v; ss2 += v * v;
    }
    sm.part[q][l] = ss; sm.part2[q][l] = ss2;
  }
  __syncthreads();
  if (t < 64) {
    float su = sm.part[0][t] + sm.part[1][t] + sm.part[2][t] + sm.part[3][t];
    float su2 = sm.part2[0][t] + sm.part2[1][t] + sm.part2[2][t] + sm.part2[3][t];
    float mu = su * (1.f / DIM_);
    float var = su2 * (1.f / DIM_) - mu * mu;
    sm.mu_s[t] = mu; sm.isd_s[t] = rsqrtf(var + EPS_);
  }
  __syncthreads();
  {
    float mu2 = sm.mu_s[l], isd2 = sm.isd_s[l];
#pragma unroll
    for (int kk = 0; kk < 2; kk++) {
      int kb2 = q * 2 + kk;
      int c0 = kb2 * 8;
      unsigned short pk[8];
#pragma unroll
      for (int e8 = 0; e8 < 8; e8++) {
        int c = c0 + e8;
        float v = (sm.u1.zb[l * 65 + c] - mu2) * isd2 * g2[c] + b2[c];
        pk[e8] = f2bf(v);
      }
      int ks2 = kb2 >> 2, qd2 = kb2 & 3;
      *(short8*)&sm.u2.zn2[(((ltile * 2 + ks2) * 4 + qd2) * 16 + n) * 8] = *(short8*)pk;
    }
  }
  __syncthreads();
  float4v acc2[4];
  acc2[0] = (float4v)0.f; acc2[1] = (float4v)0.f; acc2[2] = (float4v)0.f; acc2[3] = (float4v)0.f;
#pragma unroll
  for (int ks2 = 0; ks2 < 2; ks2++) {
    short8 bz = *(short8*)&sm.u2.zn2[((q * 2 + ks2) * 64 + tl) * 8];
    const unsigned short* fk = fsw + ks2 * 2048 + tl * 8;
    short8 f0 = *(const short8*)(fk);
    short8 f1 = *(const short8*)(fk + 512);
    short8 f2 = *(const short8*)(fk + 1024);
    short8 f3 = *(const short8*)(fk + 1536);
    acc2[0] = __builtin_amdgcn_mfma_f32_16x16x32_bf16(f0, bz, acc2[0], 0, 0, 0);
    acc2[1] = __builtin_amdgcn_mfma_f32_16x16x32_bf16(f1, bz, acc2[1], 0, 0, 0);
    acc2[2] = __builtin_amdgcn_mfma_f32_16x16x32_bf16(f2, bz, acc2[2], 0, 0, 0);
    acc2[3] = __builtin_amdgcn_mfma_f32_16x16x32_bf16(f3, bz, acc2[3], 0, 0, 0);
  }
#pragma unroll
  for (int ot = 0; ot < 4; ot++) {
#pragma unroll
    for (int r = 0; r < 4; r++) {
      int o2 = ot * 16 + quad * 4 + r;
      float sv = acc2[ot][r] + fc1_b[o2];
      float g = 0.5f * sv * (1.f + erff(sv * 0.70710678118f));
      out[((size_t)b * DIM_ + o2) * L_ + l0 + q * 16 + n] = g;
    }
  }
}

extern "C" void kernel_launch(void* const* d_in, const int* in_sizes, int n_in,
                              void* d_out, int out_size, void* d_ws, size_t ws_size,
                              hipStream_t stream) {
  const float* x    = (const float*)d_in[0];
  const float* n1w  = (const float*)d_in[1];
  const float* n1b  = (const float*)d_in[2];
  const float* drw  = (const float*)d_in[3];
  const float* drb  = (const float*)d_in[4];
  const float* n2w  = (const float*)d_in[5];
  const float* n2b  = (const float*)d_in[6];
  const float* fc1w = (const float*)d_in[7];
  const float* fc1b = (const float*)d_in[8];
  float* out = (float*)d_out;
  float* ws = (float*)d_ws;
  float* ws_a    = ws;                                  // 4*4*16384 floats
  float* ws_bsum = ws_a + (size_t)B_ * NH * L_;         // 16*256 floats
  unsigned short* wsw = (unsigned short*)(ws_bsum + B_ * NH * 256); // 163840 bf16
  unsigned short* fsw = wsw + WSWN;                     // 4096 bf16

  hipLaunchKernelGGL(k_pre, dim3(LOGITS_BLOCKS + PREP_BLOCKS), dim3(256), 0, stream,
                     drw, fc1w, x, n1w, n1b, wsw, fsw, ws_a, ws_bsum);
  hipLaunchKernelGGL(k_main, dim3(B_ * (L_ / LT)), dim3(256), 0, stream,
                     x, n1w, n1b, drb, n2w, n2b, fc1b, wsw, fsw, ws_a, ws_bsum, out);
}